// Round 7
// baseline (205.438 us; speedup 1.0000x reference)
//
#include <hip/hip_runtime.h>

// MRConv: B=4, C=192, N=10000, K=16, OUT=384
// out[b,o,n] = relu( sum_ch W[o,ch]*feat[b,ch,n] + bias[o] )
// feat[b,2c,n] = x[b,c,n]; feat[b,2c+1,n] = max_k( x[b,c,e0[b,n,k]] - x[b,c,e1[b,n,k]] )
//
// Round 7: revert to the split structure (measured best, R2) + accumulated wins:
//  k_prep   : x -> xT f16 [b][n][c], W -> f16
//  k_gather : 32 waves/CU, 2 nodes/wave, uint2 row loads, readlane SGPR
//             addressing, featT granules (interleaved x,m) via uint4 stores
//  k_gemm   : R2's 48KB global_load_lds staged MFMA GEMM (f16), nt out stores

#define NB   4
#define NC   192
#define NN   10000
#define NK   16
#define NOUT 384
#define K2C  384            // 2*C
#define NPAD 10112          // 158*64, padded node count for GEMM tiles

typedef _Float16 f16x8 __attribute__((ext_vector_type(8)));  // 4 VGPRs (MFMA A/B)
typedef _Float16 h2    __attribute__((ext_vector_type(2)));  // packed pair
typedef float    f32x4 __attribute__((ext_vector_type(4)));

__device__ inline unsigned short f2h(float f) {
    _Float16 h = (_Float16)f;
    return __builtin_bit_cast(unsigned short, h);
}

// ---------------- K1: transpose x[b][c][n] f32 -> xT[b][n][c] f16, + W -> f16 ----------------
__global__ __launch_bounds__(256) void k_prep(const float* __restrict__ x,
                                              const float* __restrict__ w,
                                              unsigned short* __restrict__ xT,
                                              unsigned short* __restrict__ wh) {
    __shared__ unsigned short tile[NC * 65];   // 192 x 64 (+1 pad)
    int gid = blockIdx.x * 256 + threadIdx.x;
    if (gid < NOUT * K2C) wh[gid] = f2h(w[gid]);       // 147456 elems

    int b  = blockIdx.x & 3;
    int nb = (blockIdx.x >> 2) * 64;
    int t  = threadIdx.x;
    const float* xb = x + (size_t)b * NC * NN;
    for (int i = 0; i < 48; ++i) {             // 192*64/256
        int idx = i * 256 + t;
        int c  = idx >> 6;
        int nl = idx & 63;
        int n  = nb + nl;
        float v = (n < NN) ? xb[(size_t)c * NN + n] : 0.f;   // coalesced along n
        tile[c * 65 + nl] = f2h(v);
    }
    __syncthreads();
    unsigned int* xTd = (unsigned int*)(xT + (size_t)b * NN * NC);  // 96 dwords / node row
    for (int i = 0; i < 24; ++i) {             // 96*64/256 packed-dword writes
        int idx = i * 256 + t;
        int nl  = idx / 96;
        int cd  = idx - nl * 96;               // dword = channels {2cd, 2cd+1}
        int n   = nb + nl;
        if (n < NN) {
            unsigned int lo = tile[(2 * cd)     * 65 + nl];
            unsigned int hi = tile[(2 * cd + 1) * 65 + nl];
            xTd[(size_t)n * 96 + cd] = lo | (hi << 16);    // coalesced along cd
        }
    }
}

// ---------------- K2: gather + max-relative -> featT granules ----------------
// grid 4*625 = 2500 blocks x 512 thr (8 waves). No LDS -> 4 blocks/CU resident
// = 32 waves/CU (full wave slots; VGPR<=64 via launch_bounds(512,8)).
// Wave owns 2 nodes; lanes 0..47 load uint2 (4 ch) of each 384B gathered row;
// packed v_pk f16 sub+max; edge indices wave-uniform via readlane (SGPR saddr).
// featT row (768B) written as 48 uint4 granules, interleaved (x_c, m_c) --
// exactly the 16B granule layout k_gemm's B-fragments consume.
__global__ __launch_bounds__(512, 8) void k_gather(const unsigned short* __restrict__ xT,
                                                   const int* __restrict__ eidx,
                                                   unsigned short* __restrict__ featT) {
    int bid  = blockIdx.x;
    int b    = bid & 3;                            // batch -> XCD pair {b, b+4}
    int tile = bid >> 2;                           // 0..624
    int wv   = threadIdx.x >> 6;                   // 0..7
    int lane = threadIdx.x & 63;

    const uint2* xr2 = (const uint2*)(xT + (size_t)b * NN * NC);   // 48 uint2 / node row
    const int* e0 = eidx + (size_t)b * NN * NK;                    // neighbors (x_j)
    const int* e1 = eidx + (size_t)NB * NN * NK + (size_t)b * NN * NK;  // centers (x_i)
    unsigned short* fb = featT + (size_t)b * NPAD * K2C;
    int nbase = tile * 16 + wv * 2;                // 2 nodes per wave, exact cover

    // edge indices for the wave's 2 nodes: 2x32 elems, lanes duplicated x2
    int ej = __builtin_nontemporal_load(&e0[(size_t)nbase * NK + (lane & 31)]);
    int ei = __builtin_nontemporal_load(&e1[(size_t)nbase * NK + (lane & 31)]);

    int dc  = (lane < 48) ? lane : 47;             // clamped granule id for loads
    bool wr = (lane < 48);                         // store mask

#pragma unroll
    for (int it = 0; it < 2; ++it) {
        int n  = nbase + it;
        uint2 jr[16], ir[16];
#pragma unroll
        for (int k = 0; k < 16; ++k) {
            int j = __builtin_amdgcn_readlane(ej, it * 16 + k);
            jr[k] = xr2[(size_t)j * 48 + dc];
        }
#pragma unroll
        for (int k = 0; k < 16; ++k) {
            int i_ = __builtin_amdgcn_readlane(ei, it * 16 + k);
            ir[k] = xr2[(size_t)i_ * 48 + dc];
        }
        uint2 cx = xr2[(size_t)n * 48 + dc];       // center row, ch 4dc..4dc+3
        h2 m0 = __builtin_bit_cast(h2, 0xFC00FC00u);   // (-inf, -inf)
        h2 m1 = m0;
#pragma unroll
        for (int k = 0; k < 16; ++k) {
            h2 dlo = __builtin_bit_cast(h2, jr[k].x) - __builtin_bit_cast(h2, ir[k].x);
            h2 dhi = __builtin_bit_cast(h2, jr[k].y) - __builtin_bit_cast(h2, ir[k].y);
            m0 = __builtin_elementwise_max(m0, dlo);   // v_pk_max_f16
            m1 = __builtin_elementwise_max(m1, dhi);
        }
        unsigned int mb0 = __builtin_bit_cast(unsigned int, m0);
        unsigned int mb1 = __builtin_bit_cast(unsigned int, m1);
        // granule dc = interleaved (x_c, m_c) for ch 4dc..4dc+3 (16B)
        uint4 g;
        g.x = (cx.x & 0xFFFFu) | (mb0 << 16);
        g.y = (cx.x >> 16)     | (mb0 & 0xFFFF0000u);
        g.z = (cx.y & 0xFFFFu) | (mb1 << 16);
        g.w = (cx.y >> 16)     | (mb1 & 0xFFFF0000u);
        if (wr) *(uint4*)(fb + (size_t)n * K2C + (size_t)dc * 8) = g;  // 768B row, coalesced
    }
}

// ---------------- K3: GEMM out[b][o][n] = relu(W @ feat + bias) ----------------
// R2's verified kernel, f16. Block: 384 outs x 64 nodes, 4 waves (each 96x64 =
// 6x4 frags of 16x16x32). featT tile (64 rows x 48 granules x 16B = 48 KB)
// staged once via global_load_lds_dwordx4 into swizzled slots
// slot(n,j) = n*48 + (j+3n)%48; W (A-operand) direct from L2.
__global__ __launch_bounds__(256, 3) void k_gemm(const unsigned short* __restrict__ wh,
                                                 const unsigned short* __restrict__ featT,
                                                 const float* __restrict__ bias,
                                                 float* __restrict__ out) {
    __shared__ unsigned short lds[64 * 48 * 8];   // 3072 granules of 16B = 48 KB
    int bid  = blockIdx.x;
    int b    = bid & 3;
    int nt   = bid >> 2;                          // 0..157
    int wv   = threadIdx.x >> 6;
    int lane = threadIdx.x & 63;
    int r    = lane & 15;
    int q    = lane >> 4;

    // ---- stage featT tile: 48 issues of 1 KB, 12 per wave ----
    const unsigned short* fbase = featT + (size_t)b * NPAD * K2C + (size_t)(nt * 64) * K2C;
#pragma unroll
    for (int ii = 0; ii < 12; ++ii) {
        int i = wv * 12 + ii;
        unsigned int g = (unsigned int)(i * 64 + lane);   // dest slot index
        unsigned int n = g / 48u;
        unsigned int p = g - n * 48u;
        int j = (int)p - (int)((3u * n) % 48u);
        if (j < 0) j += 48;
        const unsigned short* src = fbase + (size_t)n * K2C + (size_t)j * 8;
        __builtin_amdgcn_global_load_lds(
            (const __attribute__((address_space(1))) unsigned int*)src,
            (__attribute__((address_space(3))) unsigned int*)&lds[(size_t)i * 512],
            16, 0, 0);
    }

    // ---- A (W) addressing: wave covers rows wv*96 .. wv*96+95 ----
    const unsigned short* aptr = wh + (size_t)(wv * 96 + r) * K2C + q * 8;

    // B slot bases per ni: n = ni*16 + r, u0 = (q + 3n) % 48
    unsigned int nbs[4], u0[4];
#pragma unroll
    for (int ni = 0; ni < 4; ++ni) {
        unsigned int n_ = ni * 16 + r;
        nbs[ni] = n_ * 48u;
        u0[ni]  = ((unsigned int)q + 3u * n_) % 48u;
    }

    f32x4 acc[6][4];
#pragma unroll
    for (int mi = 0; mi < 6; ++mi)
#pragma unroll
        for (int ni = 0; ni < 4; ++ni)
            acc[mi][ni] = (f32x4){0.f, 0.f, 0.f, 0.f};

    __syncthreads();   // drains global_load_lds (vmcnt(0) before s_barrier)

#pragma unroll 2
    for (int t = 0; t < 12; ++t) {
        f16x8 a[6], bb[4];
#pragma unroll
        for (int mi = 0; mi < 6; ++mi)
            a[mi] = *(const f16x8*)(aptr + (size_t)mi * 16 * K2C + t * 32);
#pragma unroll
        for (int ni = 0; ni < 4; ++ni) {
            unsigned int u = u0[ni] + 4u * t;
            if (u >= 48u) u -= 48u;
            bb[ni] = *(const f16x8*)(lds + (size_t)(nbs[ni] + u) * 8);
        }
#pragma unroll
        for (int mi = 0; mi < 6; ++mi)
#pragma unroll
            for (int ni = 0; ni < 4; ++ni)
                acc[mi][ni] = __builtin_amdgcn_mfma_f32_16x16x32_f16(a[mi], bb[ni], acc[mi][ni], 0, 0, 0);
    }

    float* ob = out + (size_t)b * NOUT * NN;
#pragma unroll
    for (int mi = 0; mi < 6; ++mi) {
        int obase = wv * 96 + mi * 16 + q * 4;
        float4 b4 = *(const float4*)(bias + obase);   // 16B-aligned
        float bv[4] = {b4.x, b4.y, b4.z, b4.w};
#pragma unroll
        for (int ni = 0; ni < 4; ++ni) {
            int n = nt * 64 + ni * 16 + r;
            if (n < NN) {
#pragma unroll
                for (int rr = 0; rr < 4; ++rr) {
                    float val = fmaxf(acc[mi][ni][rr] + bv[rr], 0.f);
                    __builtin_nontemporal_store(val, &ob[(size_t)(obase + rr) * NN + n]);
                }
            }
        }
    }
}

extern "C" void kernel_launch(void* const* d_in, const int* in_sizes, int n_in,
                              void* d_out, int out_size, void* d_ws, size_t ws_size,
                              hipStream_t stream) {
    const float* x    = (const float*)d_in[0];   // [4,192,10000,1]
    const int*   eidx = (const int*)d_in[1];     // [2,4,10000,16]
    const float* w    = (const float*)d_in[2];   // [384,384]
    const float* bias = (const float*)d_in[3];   // [384]
    float* out = (float*)d_out;                  // [4,384,10000,1,1]

    // workspace: xT [4][10000][192] f16 (15.36 MB) | featT [4][10112][384] f16
    // (31.06 MB) | wh [384][384] f16 (0.29 MB)
    unsigned short* xT    = (unsigned short*)d_ws;
    unsigned short* featT = xT + (size_t)NB * NN * NC;
    unsigned short* wh    = featT + (size_t)NB * NPAD * K2C;

    hipLaunchKernelGGL(k_prep,   dim3(4 * 157), dim3(256), 0, stream, x, w, xT, wh);
    hipLaunchKernelGGL(k_gather, dim3(4 * 625), dim3(512), 0, stream, xT, eidx, featT);
    hipLaunchKernelGGL(k_gemm,   dim3(4 * 158), dim3(256), 0, stream, wh, featT, bias, out);
}